// Round 7
// baseline (320.401 us; speedup 1.0000x reference)
//
#include <hip/hip_runtime.h>

#define N_NODES 100000
#define N_EDGES 1250000
#define D 64
#define BUCKET_BITS 6                  // 64 nodes / bucket
#define BUCKET_SZ 64
#define NBUCK 1563                     // ceil(100000/64)
#define CAP 1024                       // fixed bucket capacity (mean 800, sigma ~28; max~908)
#define TR_BLOCKS ((N_NODES + 63) / 64)          // 1563 (also the fused grid)
#define EPS 800                        // edges per block's bin slice: 1563*800 >= 1.25M

// ---------------------------------------------------------------------------
// Workspace layout (bytes):
//   packed  @ 0          : NBUCK*CAP int2 = 12,804,096  (src|dlocal<<20, e)
//   gcursor @ 12,804,096 : NBUCK i32      =      6,252  (hipMemsetAsync zeroed)
//   g16     @ 12,810,368 : N*64 bf16      = 12,800,000  (bf16(h @ W^T))
// total ~= 25.6 MB
// ---------------------------------------------------------------------------

typedef __attribute__((ext_vector_type(8))) short bf16x8;   // MFMA A/B frag (4 VGPR)
typedef __attribute__((ext_vector_type(4))) float f32x4;    // MFMA C/D frag

__device__ __forceinline__ unsigned bf16_rne(float x) {
    unsigned u = __float_as_uint(x);
    return (u + 0x7FFFu + ((u >> 16) & 1u)) >> 16;
}
__device__ __forceinline__ float bf16_to_f(unsigned short v) {
    return __uint_as_float(((unsigned)v) << 16);
}

// Split fp32 -> bf16 hi + bf16 lo with x ~= hi + lo (residual ~2^-18 rel).
__device__ __forceinline__ void bf16_split(float x, short& hi, short& lo) {
    unsigned hb = bf16_rne(x);
    float fh = __uint_as_float(hb << 16);
    hi = (short)hb;
    lo = (short)bf16_rne(x - fh);
}

// Fused transform + bin, UNIFORM blocks (R6 post-mortem: VGPR=60 vs ~130
// needed -> scratch spills -> 87% idle; WRITE_SIZE showed ~15 MB of spill
// traffic). Fixes: (a) B-fragment load/split lives inside the kk/nt loop so
// only 8 B-regs are live at once (was 64); (b) bin path is a register-light
// edge slice appended after transform in EVERY block (no lhist, no EPT
// arrays, no divergent role branch) -- 4 loads in flight, then 4 direct
// global atomicAdd+scatter; (c) __launch_bounds__(256,4) -> VGPR cap 128.
__global__ __launch_bounds__(256, 4) void transform_bin_kernel(const float* __restrict__ h,
                                                               const float* __restrict__ W,
                                                               unsigned short* __restrict__ g16,
                                                               const int* __restrict__ src,
                                                               const int* __restrict__ dst,
                                                               const float* __restrict__ e,
                                                               int* __restrict__ gcursor,
                                                               int2* __restrict__ packed) {
    __shared__ unsigned short sh[64 * D];   // 8 KB

    int t = threadIdx.x;
    int bx = blockIdx.x;
    int lane = t & 63;
    int w = t >> 6;
    int li = lane & 15;      // A row / B col within 16-tile
    int lg = lane >> 4;      // k-group (0..3), 8 contiguous k each
    int nodebase = bx * 64 + w * 16;

    int arow = nodebase + li;
    if (arow > N_NODES - 1) arow = N_NODES - 1;

    f32x4 acc[4];
#pragma unroll
    for (int nt = 0; nt < 4; ++nt) acc[nt] = (f32x4){0.f, 0.f, 0.f, 0.f};

#pragma unroll
    for (int kk = 0; kk < 2; ++kk) {
        // A fragment for this k-step (8 VGPRs hi + 8 lo... 4+4 as bf16x8)
        const float* hp = h + (long)arow * D + kk * 32 + lg * 8;
        float4 h0 = *(const float4*)hp;
        float4 h1 = *(const float4*)(hp + 4);
        float av[8] = {h0.x, h0.y, h0.z, h0.w, h1.x, h1.y, h1.z, h1.w};
        bf16x8 ahi, alo;
#pragma unroll
        for (int q = 0; q < 8; ++q) { short a, b; bf16_split(av[q], a, b); ahi[q] = a; alo[q] = b; }

#pragma unroll
        for (int nt = 0; nt < 4; ++nt) {
            // B fragment loaded/split here -> only one (nt,kk) pair live at a time
            const float* wp = W + (nt * 16 + li) * D + kk * 32 + lg * 8;
            float4 w0 = *(const float4*)wp;
            float4 w1 = *(const float4*)(wp + 4);
            float bv[8] = {w0.x, w0.y, w0.z, w0.w, w1.x, w1.y, w1.z, w1.w};
            bf16x8 bhi, blo;
#pragma unroll
            for (int q = 0; q < 8; ++q) { short a, b; bf16_split(bv[q], a, b); bhi[q] = a; blo[q] = b; }

            acc[nt] = __builtin_amdgcn_mfma_f32_16x16x32_bf16(ahi, bhi, acc[nt], 0, 0, 0);
            acc[nt] = __builtin_amdgcn_mfma_f32_16x16x32_bf16(ahi, blo, acc[nt], 0, 0, 0);
            acc[nt] = __builtin_amdgcn_mfma_f32_16x16x32_bf16(alo, bhi, acc[nt], 0, 0, 0);
        }
    }

    // C/D layout (m89): col = lane&15, row = (lane>>4)*4 + reg. Stage in LDS.
#pragma unroll
    for (int nt = 0; nt < 4; ++nt) {
#pragma unroll
        for (int r = 0; r < 4; ++r) {
            sh[(w * 16 + lg * 4 + r) * D + nt * 16 + li] = (unsigned short)bf16_rne(acc[nt][r]);
        }
    }
    __syncthreads();

    // coalesced flush: 512 uint4 per block, 2 per thread.
    const uint4* s4 = (const uint4*)sh;
    uint4* g4 = (uint4*)(g16 + (long)bx * 64 * D);
#pragma unroll
    for (int i = t; i < 512; i += 256) {
        int n = bx * 64 + (i >> 3);
        if (n < N_NODES) g4[i] = s4[i];
    }

    // ---- bin slice: 800 edges/block, register-light, 4 loads in flight ----
    int ebase = bx * EPS;
    int i0 = ebase + t, i1 = i0 + 256, i2 = i0 + 512, i3 = i0 + 768;
    int eend = ebase + EPS;
    if (eend > N_EDGES) eend = N_EDGES;
    bool v0 = i0 < eend, v1 = i1 < eend, v2 = i2 < eend, v3 = i3 < eend;
    int d0 = 0, d1 = 0, d2 = 0, d3 = 0;
    int s0 = 0, s1 = 0, s2 = 0, s3 = 0;
    float e0 = 0.f, e1 = 0.f, e2 = 0.f, e3 = 0.f;
    if (v0) { d0 = dst[i0]; s0 = src[i0]; e0 = e[i0]; }
    if (v1) { d1 = dst[i1]; s1 = src[i1]; e1 = e[i1]; }
    if (v2) { d2 = dst[i2]; s2 = src[i2]; e2 = e[i2]; }
    if (v3) { d3 = dst[i3]; s3 = src[i3]; e3 = e[i3]; }
    if (v0) {
        int bk = d0 >> BUCKET_BITS;
        int pos = atomicAdd(&gcursor[bk], 1);
        if (pos < CAP) packed[bk * CAP + pos] = make_int2(s0 | ((d0 & (BUCKET_SZ - 1)) << 20), __float_as_int(e0));
    }
    if (v1) {
        int bk = d1 >> BUCKET_BITS;
        int pos = atomicAdd(&gcursor[bk], 1);
        if (pos < CAP) packed[bk * CAP + pos] = make_int2(s1 | ((d1 & (BUCKET_SZ - 1)) << 20), __float_as_int(e1));
    }
    if (v2) {
        int bk = d2 >> BUCKET_BITS;
        int pos = atomicAdd(&gcursor[bk], 1);
        if (pos < CAP) packed[bk * CAP + pos] = make_int2(s2 | ((d2 & (BUCKET_SZ - 1)) << 20), __float_as_int(e2));
    }
    if (v3) {
        int bk = d3 >> BUCKET_BITS;
        int pos = atomicAdd(&gcursor[bk], 1);
        if (pos < CAP) packed[bk * CAP + pos] = make_int2(s3 | ((d3 & (BUCKET_SZ - 1)) << 20), __float_as_int(e3));
    }
}

// Per-bucket gather, 512 threads = 8 waves x 8 nodes: counting-sort edges
// by node in LDS (single packed read, register-cached; wave-0 shuffle scan),
// then per-node 8-deep-unrolled register accumulation (R3 lesson: no
// per-edge LDS writes in the hot loop).
__global__ __launch_bounds__(512) void gather_bucket_kernel(const unsigned short* __restrict__ g16,
                                                            const int2* __restrict__ packed,
                                                            const int* __restrict__ gcursor,
                                                            const float* __restrict__ bias,
                                                            float* __restrict__ out) {
    __shared__ int2 eds[CAP];
    __shared__ int nhist[BUCKET_SZ];
    __shared__ int nbase[BUCKET_SZ];
    __shared__ int ncur[BUCKET_SZ];

    int t = threadIdx.x;
    int bk = blockIdx.x;
    int start = bk * CAP;
    int cnt = gcursor[bk];
    if (cnt > CAP) cnt = CAP;

    if (t < BUCKET_SZ) nhist[t] = 0;
    __syncthreads();

    // single packed read, cached in named registers (static indexing)
    int2 pa = make_int2(0, 0), pb = pa;
    bool va = t < cnt, vb = t + 512 < cnt;
    if (va) pa = packed[start + t];
    if (vb) pb = packed[start + t + 512];
    if (va) atomicAdd(&nhist[(pa.x >> 20) & (BUCKET_SZ - 1)], 1);
    if (vb) atomicAdd(&nhist[(pb.x >> 20) & (BUCKET_SZ - 1)], 1);
    __syncthreads();

    // wave-0 shuffle inclusive scan over 64 bins -> exclusive bases
    if (t < BUCKET_SZ) {
        int c = nhist[t];
        int v = c;
#pragma unroll
        for (int off = 1; off < BUCKET_SZ; off <<= 1) {
            int x = __shfl_up(v, off, 64);
            if (t >= off) v += x;
        }
        nbase[t] = v - c;
        ncur[t] = v - c;
    }
    __syncthreads();

    // scatter from registers into node-sorted LDS order
    if (va) { int dl = (pa.x >> 20) & (BUCKET_SZ - 1); eds[atomicAdd(&ncur[dl], 1)] = pa; }
    if (vb) { int dl = (pb.x >> 20) & (BUCKET_SZ - 1); eds[atomicAdd(&ncur[dl], 1)] = pb; }
    __syncthreads();

    // per-node gather: wave w handles nodes [w*8, w*8+8); lane = feature
    int w = t >> 6;
    int lane = t & 63;
    float bv = bias[lane];
    for (int jj = 0; jj < 8; ++jj) {
        int n = w * 8 + jj;
        int gn = bk * BUCKET_SZ + n;
        int s = nbase[n];
        int c = nhist[n];
        float acc = bv;
        int k = 0;
        for (; k + 8 <= c; k += 8) {           // 8 independent 128-B lines in flight
            int2 q0 = eds[s + k + 0], q1 = eds[s + k + 1];
            int2 q2 = eds[s + k + 2], q3 = eds[s + k + 3];
            int2 q4 = eds[s + k + 4], q5 = eds[s + k + 5];
            int2 q6 = eds[s + k + 6], q7 = eds[s + k + 7];
            float g0 = bf16_to_f(g16[(long)(q0.x & 0xFFFFF) * D + lane]);
            float g1 = bf16_to_f(g16[(long)(q1.x & 0xFFFFF) * D + lane]);
            float g2 = bf16_to_f(g16[(long)(q2.x & 0xFFFFF) * D + lane]);
            float g3 = bf16_to_f(g16[(long)(q3.x & 0xFFFFF) * D + lane]);
            float g4 = bf16_to_f(g16[(long)(q4.x & 0xFFFFF) * D + lane]);
            float g5 = bf16_to_f(g16[(long)(q5.x & 0xFFFFF) * D + lane]);
            float g6 = bf16_to_f(g16[(long)(q6.x & 0xFFFFF) * D + lane]);
            float g7 = bf16_to_f(g16[(long)(q7.x & 0xFFFFF) * D + lane]);
            acc += __int_as_float(q0.y) * g0;
            acc += __int_as_float(q1.y) * g1;
            acc += __int_as_float(q2.y) * g2;
            acc += __int_as_float(q3.y) * g3;
            acc += __int_as_float(q4.y) * g4;
            acc += __int_as_float(q5.y) * g5;
            acc += __int_as_float(q6.y) * g6;
            acc += __int_as_float(q7.y) * g7;
        }
        if (k + 4 <= c) {
            int2 q0 = eds[s + k + 0], q1 = eds[s + k + 1];
            int2 q2 = eds[s + k + 2], q3 = eds[s + k + 3];
            float g0 = bf16_to_f(g16[(long)(q0.x & 0xFFFFF) * D + lane]);
            float g1 = bf16_to_f(g16[(long)(q1.x & 0xFFFFF) * D + lane]);
            float g2 = bf16_to_f(g16[(long)(q2.x & 0xFFFFF) * D + lane]);
            float g3 = bf16_to_f(g16[(long)(q3.x & 0xFFFFF) * D + lane]);
            acc += __int_as_float(q0.y) * g0;
            acc += __int_as_float(q1.y) * g1;
            acc += __int_as_float(q2.y) * g2;
            acc += __int_as_float(q3.y) * g3;
            k += 4;
        }
        for (; k < c; ++k) {
            int2 q = eds[s + k];
            acc += __int_as_float(q.y) * bf16_to_f(g16[(long)(q.x & 0xFFFFF) * D + lane]);
        }
        if (gn < N_NODES) out[(long)gn * D + lane] = acc;
    }
}

// ---------------------------------------------------------------------------
extern "C" void kernel_launch(void* const* d_in, const int* in_sizes, int n_in,
                              void* d_out, int out_size, void* d_ws, size_t ws_size,
                              hipStream_t stream) {
    const float* h   = (const float*)d_in[0];
    const float* e   = (const float*)d_in[1];
    const int*   src = (const int*)d_in[2];
    const int*   dst = (const int*)d_in[3];
    const float* W   = (const float*)d_in[4];
    const float* b   = (const float*)d_in[5];
    float* out = (float*)d_out;

    char* ws = (char*)d_ws;
    int2*           packed  = (int2*)          (ws);
    int*            gcursor = (int*)           (ws + 12804096);
    unsigned short* g16     = (unsigned short*)(ws + 12810368);

    // 1) zero bucket cursors (workspace is poison-filled every iteration)
    hipMemsetAsync(gcursor, 0, NBUCK * sizeof(int), stream);

    // 2) fused transform + bin-slice, uniform blocks (no spills, no role branch)
    transform_bin_kernel<<<TR_BLOCKS, 256, 0, stream>>>(h, W, g16, src, dst, e, gcursor, packed);

    // 3) per-bucket counting-sort gather + bias (8 waves x 8 nodes, MLP-8)
    gather_bucket_kernel<<<NBUCK, 512, 0, stream>>>(g16, packed, gcursor, b, out);
}

// Round 8
// 163.508 us; speedup vs baseline: 1.9595x; 1.9595x over previous
//
#include <hip/hip_runtime.h>

#define N_NODES 100000
#define N_EDGES 1250000
#define D 64
#define BUCKET_BITS 6                  // 64 nodes / bucket
#define BUCKET_SZ 64
#define NBUCK 1563                     // ceil(100000/64)
#define CAP 1024                       // fixed bucket capacity (mean 800, sigma ~28; max~908)
#define EPT 16                         // edges per thread per pass in bin path
#define EPB (EPT * 256)                // 4096 edges per bin block
#define BIN_BLOCKS ((N_EDGES + EPB - 1) / EPB)   // 306
#define TR_BLOCKS 782                  // 2 tiles (128 nodes) each: 782*128 = 100096
#define FUSED_BLOCKS (TR_BLOCKS + BIN_BLOCKS)    // 1088

// ---------------------------------------------------------------------------
// Workspace layout (bytes):
//   packed  @ 0          : NBUCK*CAP int2 = 12,804,096  (src|dlocal<<20, e)
//   gcursor @ 12,804,096 : NBUCK i32      =      6,252  (hipMemsetAsync zeroed)
//   g16     @ 12,810,368 : N*64 bf16      = 12,800,000  (bf16(h @ W^T))
// total ~= 25.6 MB
// ---------------------------------------------------------------------------

typedef __attribute__((ext_vector_type(8))) short bf16x8;   // MFMA A/B frag (4 VGPR)
typedef __attribute__((ext_vector_type(4))) float f32x4;    // MFMA C/D frag

__device__ __forceinline__ unsigned bf16_rne(float x) {
    unsigned u = __float_as_uint(x);
    return (u + 0x7FFFu + ((u >> 16) & 1u)) >> 16;
}
__device__ __forceinline__ float bf16_to_f(unsigned short v) {
    return __uint_as_float(((unsigned)v) << 16);
}

// Split fp32 -> bf16 hi + bf16 lo with x ~= hi + lo (residual ~2^-18 rel).
__device__ __forceinline__ void bf16_split(float x, short& hi, short& lo) {
    unsigned hb = bf16_rne(x);
    float fh = __uint_as_float(hb << 16);
    hi = (short)hb;
    lo = (short)bf16_rne(x - fh);
}

// One 64-node tile: split pre-loaded h fragments, MFMA against W (L1-hot,
// loaded/split per (nt,kk) so only 8 B-regs live at once), write bf16 C
// into the given LDS buffer. C/D layout (m89): col=lane&15, row=(lane>>4)*4+reg.
__device__ __forceinline__ void transform_tile(float4 hk0a, float4 hk0b,
                                               float4 hk1a, float4 hk1b,
                                               const float* __restrict__ W,
                                               unsigned short* __restrict__ sh,
                                               int li, int lg, int w) {
    bf16x8 ahi[2], alo[2];
    {
        float av[8] = {hk0a.x, hk0a.y, hk0a.z, hk0a.w, hk0b.x, hk0b.y, hk0b.z, hk0b.w};
#pragma unroll
        for (int q = 0; q < 8; ++q) { short a, b; bf16_split(av[q], a, b); ahi[0][q] = a; alo[0][q] = b; }
    }
    {
        float av[8] = {hk1a.x, hk1a.y, hk1a.z, hk1a.w, hk1b.x, hk1b.y, hk1b.z, hk1b.w};
#pragma unroll
        for (int q = 0; q < 8; ++q) { short a, b; bf16_split(av[q], a, b); ahi[1][q] = a; alo[1][q] = b; }
    }

    f32x4 acc[4];
#pragma unroll
    for (int nt = 0; nt < 4; ++nt) acc[nt] = (f32x4){0.f, 0.f, 0.f, 0.f};

#pragma unroll
    for (int kk = 0; kk < 2; ++kk) {
#pragma unroll
        for (int nt = 0; nt < 4; ++nt) {
            const float* wp = W + (nt * 16 + li) * D + kk * 32 + lg * 8;
            float4 w0 = *(const float4*)wp;
            float4 w1 = *(const float4*)(wp + 4);
            float bv[8] = {w0.x, w0.y, w0.z, w0.w, w1.x, w1.y, w1.z, w1.w};
            bf16x8 bhi, blo;
#pragma unroll
            for (int q = 0; q < 8; ++q) { short a, b; bf16_split(bv[q], a, b); bhi[q] = a; blo[q] = b; }
            acc[nt] = __builtin_amdgcn_mfma_f32_16x16x32_bf16(ahi[kk], bhi, acc[nt], 0, 0, 0);
            acc[nt] = __builtin_amdgcn_mfma_f32_16x16x32_bf16(ahi[kk], blo, acc[nt], 0, 0, 0);
            acc[nt] = __builtin_amdgcn_mfma_f32_16x16x32_bf16(alo[kk], bhi, acc[nt], 0, 0, 0);
        }
    }

#pragma unroll
    for (int nt = 0; nt < 4; ++nt) {
#pragma unroll
        for (int r = 0; r < 4; ++r) {
            sh[(w * 16 + lg * 4 + r) * D + nt * 16 + li] = (unsigned short)bf16_rne(acc[nt][r]);
        }
    }
}

// Fused transform + bin, interleaved roles (1 bin per 3 blocks while bin ids
// last). Transform blocks process TWO 64-node tiles with all 8 h-loads
// issued up-front (in-wave MLP to cover HBM latency; R6's 1-load-in-flight
// structure was 87% idle) and double-buffered LDS flush so tile-1 compute
// overlaps tile-0 stores. Bin path is register-light TWO-PASS (no per-edge
// arrays -> no spills; R7 lesson: per-edge global atomics are catastrophic,
// so aggregation stays in LDS with one global atomic per nonzero bucket).
__global__ __launch_bounds__(256) void transform_bin_kernel(const float* __restrict__ h,
                                                            const float* __restrict__ W,
                                                            unsigned short* __restrict__ g16,
                                                            const int* __restrict__ src,
                                                            const int* __restrict__ dst,
                                                            const float* __restrict__ e,
                                                            int* __restrict__ gcursor,
                                                            int2* __restrict__ packed) {
    __shared__ __align__(16) char smem_raw[16384];  // union: 2x8KB sh | lhist+lcur (12.5KB)

    int t = threadIdx.x;
    int bx = blockIdx.x;
    bool is_bin = ((bx % 3) == 2) && (bx / 3 < BIN_BLOCKS);

    if (!is_bin) {
        // ================= transform path: 2 tiles, pipelined =================
        int nb = (bx + 1) / 3; if (nb > BIN_BLOCKS) nb = BIN_BLOCKS;
        int trb = bx - nb;                         // 0..781 bijective
        int lane = t & 63;
        int w = t >> 6;
        int li = lane & 15;
        int lg = lane >> 4;

        int base0 = trb * 128 + w * 16;            // tile 0
        int base1 = base0 + 64;                    // tile 1
        int arow0 = base0 + li; if (arow0 > N_NODES - 1) arow0 = N_NODES - 1;
        int arow1 = base1 + li; if (arow1 > N_NODES - 1) arow1 = N_NODES - 1;

        // issue ALL h loads up-front: 8 independent 16-B loads in flight
        const float* hp0 = h + (long)arow0 * D + lg * 8;
        const float* hp1 = h + (long)arow1 * D + lg * 8;
        float4 a0k0a = *(const float4*)(hp0);
        float4 a0k0b = *(const float4*)(hp0 + 4);
        float4 a0k1a = *(const float4*)(hp0 + 32);
        float4 a0k1b = *(const float4*)(hp0 + 36);
        float4 a1k0a = *(const float4*)(hp1);
        float4 a1k0b = *(const float4*)(hp1 + 4);
        float4 a1k1a = *(const float4*)(hp1 + 32);
        float4 a1k1b = *(const float4*)(hp1 + 36);

        unsigned short* sh0 = (unsigned short*)smem_raw;
        unsigned short* sh1 = sh0 + 64 * D;

        // tile 0: compute -> stage -> barrier -> flush (stores are async)
        transform_tile(a0k0a, a0k0b, a0k1a, a0k1b, W, sh0, li, lg, w);
        __syncthreads();
        {
            const uint4* s4 = (const uint4*)sh0;
            uint4* g4 = (uint4*)(g16 + (long)base0 * 0 + (long)(trb * 128) * D);
#pragma unroll
            for (int i = t; i < 512; i += 256) {
                int n = trb * 128 + (i >> 3);
                if (n < N_NODES) g4[i] = s4[i];
            }
        }

        // tile 1: independent buffer -> compute overlaps tile-0 flush
        transform_tile(a1k0a, a1k0b, a1k1a, a1k1b, W, sh1, li, lg, w);
        __syncthreads();
        {
            const uint4* s4 = (const uint4*)sh1;
            uint4* g4 = (uint4*)(g16 + (long)(trb * 128 + 64) * D);
#pragma unroll
            for (int i = t; i < 512; i += 256) {
                int n = trb * 128 + 64 + (i >> 3);
                if (n < N_NODES) g4[i] = s4[i];
            }
        }
    } else {
        // ================= bin path: two-pass, register-light =================
        int* lhist = (int*)smem_raw;               // NBUCK counts -> global bases
        int* lcur  = lhist + NBUCK;                // NBUCK local cursors
        int cb = bx / 3;                           // 0..305
        int base = cb * EPB;

        for (int j = t; j < NBUCK; j += 256) { lhist[j] = 0; lcur[j] = 0; }
        __syncthreads();

        // pass 1: histogram dst buckets (no per-edge state kept)
#pragma unroll 4
        for (int j = 0; j < EPT; ++j) {
            int i = base + j * 256 + t;
            if (i < N_EDGES) atomicAdd(&lhist[dst[i] >> BUCKET_BITS], 1);
        }
        __syncthreads();

        // reserve contiguous global ranges: one atomic per nonzero bucket
        for (int x = t; x < NBUCK; x += 256) {
            int c = lhist[x];
            lhist[x] = (c > 0) ? atomicAdd(&gcursor[x], c) : 0;
        }
        __syncthreads();

        // pass 2: re-read edges, scatter to reserved positions
#pragma unroll 4
        for (int j = 0; j < EPT; ++j) {
            int i = base + j * 256 + t;
            if (i < N_EDGES) {
                int d = dst[i];
                int bk = d >> BUCKET_BITS;
                int pos = lhist[bk] + atomicAdd(&lcur[bk], 1);
                if (pos < CAP)
                    packed[bk * CAP + pos] = make_int2(src[i] | ((d & (BUCKET_SZ - 1)) << 20),
                                                       __float_as_int(e[i]));
            }
        }
    }
}

// Per-bucket gather, 512 threads = 8 waves x 8 nodes: counting-sort edges
// by node in LDS (single packed read, register-cached; wave-0 shuffle scan),
// then per-node 8-deep-unrolled register accumulation (R3 lesson: no
// per-edge LDS writes in the hot loop).
__global__ __launch_bounds__(512) void gather_bucket_kernel(const unsigned short* __restrict__ g16,
                                                            const int2* __restrict__ packed,
                                                            const int* __restrict__ gcursor,
                                                            const float* __restrict__ bias,
                                                            float* __restrict__ out) {
    __shared__ int2 eds[CAP];
    __shared__ int nhist[BUCKET_SZ];
    __shared__ int nbase[BUCKET_SZ];
    __shared__ int ncur[BUCKET_SZ];

    int t = threadIdx.x;
    int bk = blockIdx.x;
    int start = bk * CAP;
    int cnt = gcursor[bk];
    if (cnt > CAP) cnt = CAP;

    if (t < BUCKET_SZ) nhist[t] = 0;
    __syncthreads();

    // single packed read, cached in named registers (static indexing)
    int2 pa = make_int2(0, 0), pb = pa;
    bool va = t < cnt, vb = t + 512 < cnt;
    if (va) pa = packed[start + t];
    if (vb) pb = packed[start + t + 512];
    if (va) atomicAdd(&nhist[(pa.x >> 20) & (BUCKET_SZ - 1)], 1);
    if (vb) atomicAdd(&nhist[(pb.x >> 20) & (BUCKET_SZ - 1)], 1);
    __syncthreads();

    // wave-0 shuffle inclusive scan over 64 bins -> exclusive bases
    if (t < BUCKET_SZ) {
        int c = nhist[t];
        int v = c;
#pragma unroll
        for (int off = 1; off < BUCKET_SZ; off <<= 1) {
            int x = __shfl_up(v, off, 64);
            if (t >= off) v += x;
        }
        nbase[t] = v - c;
        ncur[t] = v - c;
    }
    __syncthreads();

    // scatter from registers into node-sorted LDS order
    if (va) { int dl = (pa.x >> 20) & (BUCKET_SZ - 1); eds[atomicAdd(&ncur[dl], 1)] = pa; }
    if (vb) { int dl = (pb.x >> 20) & (BUCKET_SZ - 1); eds[atomicAdd(&ncur[dl], 1)] = pb; }
    __syncthreads();

    // per-node gather: wave w handles nodes [w*8, w*8+8); lane = feature
    int w = t >> 6;
    int lane = t & 63;
    float bv = bias[lane];
    for (int jj = 0; jj < 8; ++jj) {
        int n = w * 8 + jj;
        int gn = bk * BUCKET_SZ + n;
        int s = nbase[n];
        int c = nhist[n];
        float acc = bv;
        int k = 0;
        for (; k + 8 <= c; k += 8) {           // 8 independent 128-B lines in flight
            int2 q0 = eds[s + k + 0], q1 = eds[s + k + 1];
            int2 q2 = eds[s + k + 2], q3 = eds[s + k + 3];
            int2 q4 = eds[s + k + 4], q5 = eds[s + k + 5];
            int2 q6 = eds[s + k + 6], q7 = eds[s + k + 7];
            float g0 = bf16_to_f(g16[(long)(q0.x & 0xFFFFF) * D + lane]);
            float g1 = bf16_to_f(g16[(long)(q1.x & 0xFFFFF) * D + lane]);
            float g2 = bf16_to_f(g16[(long)(q2.x & 0xFFFFF) * D + lane]);
            float g3 = bf16_to_f(g16[(long)(q3.x & 0xFFFFF) * D + lane]);
            float g4 = bf16_to_f(g16[(long)(q4.x & 0xFFFFF) * D + lane]);
            float g5 = bf16_to_f(g16[(long)(q5.x & 0xFFFFF) * D + lane]);
            float g6 = bf16_to_f(g16[(long)(q6.x & 0xFFFFF) * D + lane]);
            float g7 = bf16_to_f(g16[(long)(q7.x & 0xFFFFF) * D + lane]);
            acc += __int_as_float(q0.y) * g0;
            acc += __int_as_float(q1.y) * g1;
            acc += __int_as_float(q2.y) * g2;
            acc += __int_as_float(q3.y) * g3;
            acc += __int_as_float(q4.y) * g4;
            acc += __int_as_float(q5.y) * g5;
            acc += __int_as_float(q6.y) * g6;
            acc += __int_as_float(q7.y) * g7;
        }
        if (k + 4 <= c) {
            int2 q0 = eds[s + k + 0], q1 = eds[s + k + 1];
            int2 q2 = eds[s + k + 2], q3 = eds[s + k + 3];
            float g0 = bf16_to_f(g16[(long)(q0.x & 0xFFFFF) * D + lane]);
            float g1 = bf16_to_f(g16[(long)(q1.x & 0xFFFFF) * D + lane]);
            float g2 = bf16_to_f(g16[(long)(q2.x & 0xFFFFF) * D + lane]);
            float g3 = bf16_to_f(g16[(long)(q3.x & 0xFFFFF) * D + lane]);
            acc += __int_as_float(q0.y) * g0;
            acc += __int_as_float(q1.y) * g1;
            acc += __int_as_float(q2.y) * g2;
            acc += __int_as_float(q3.y) * g3;
            k += 4;
        }
        for (; k < c; ++k) {
            int2 q = eds[s + k];
            acc += __int_as_float(q.y) * bf16_to_f(g16[(long)(q.x & 0xFFFFF) * D + lane]);
        }
        if (gn < N_NODES) out[(long)gn * D + lane] = acc;
    }
}

// ---------------------------------------------------------------------------
extern "C" void kernel_launch(void* const* d_in, const int* in_sizes, int n_in,
                              void* d_out, int out_size, void* d_ws, size_t ws_size,
                              hipStream_t stream) {
    const float* h   = (const float*)d_in[0];
    const float* e   = (const float*)d_in[1];
    const int*   src = (const int*)d_in[2];
    const int*   dst = (const int*)d_in[3];
    const float* W   = (const float*)d_in[4];
    const float* b   = (const float*)d_in[5];
    float* out = (float*)d_out;

    char* ws = (char*)d_ws;
    int2*           packed  = (int2*)          (ws);
    int*            gcursor = (int*)           (ws + 12804096);
    unsigned short* g16     = (unsigned short*)(ws + 12810368);

    // 1) zero bucket cursors (workspace is poison-filled every iteration)
    hipMemsetAsync(gcursor, 0, NBUCK * sizeof(int), stream);

    // 2) fused transform (2-tile pipelined) + two-pass bin, interleaved 2:1
    transform_bin_kernel<<<FUSED_BLOCKS, 256, 0, stream>>>(h, W, g16, src, dst, e, gcursor, packed);

    // 3) per-bucket counting-sort gather + bias (8 waves x 8 nodes, MLP-8)
    gather_bucket_kernel<<<NBUCK, 512, 0, stream>>>(g16, packed, gcursor, b, out);
}